// Round 8
// baseline (401.423 us; speedup 1.0000x reference)
//
#include <hip/hip_runtime.h>

// Problem constants
#define NPOS 32768          // B*H*W = 32*32*32
#define DDIM 256
#define KCODE 1024
#define HW 1024             // H*W
#define BSTRIDE (256*1024)  // D*H*W per batch element
#define OUT0_SIZE 8388608   // B*D*H*W
#define OUT1_SIZE 32768

// ws layout (4-byte units):
//  [0 .. 262143]        ET    : transposed codebook [d][k]        (float)
//  [262144 .. 327679]   zn2   : per-position pairwise HALVES      (float, 2*32768)
//  [327680 .. 328703]   en    : ||e_k||^2 numpy-pairwise f32      (float, 1024)
//  [328704 .. 394239]   packed: (f32bits(d)<<32)|k per pos        (u64, 32768)
#define WS_ET     0
#define WS_ZN2    262144
#define WS_EN     327680
#define WS_PACKED 328704   // *4 bytes is 8-aligned

// ---------------------------------------------------------------------------
// K1: fused prep. grid 324 blocks x 256 threads:
//   [0,256)   : zn halves (numpy pairwise 128-blocks) + packed init (+loss 0)
//   [256,260) : en[k] numpy-pairwise
//   [260,324) : 64x64 LDS-tiled transpose cb -> ET
// numpy pairwise for n=256 = fl(half0+half1); halves computed in separate
// threads (bitwise-identical chains), merged with __fadd_rn in vq_argmin.
__global__ void vq_prep(const float* __restrict__ z,
                        const float* __restrict__ cb,
                        float* __restrict__ ws_f,
                        unsigned long long* __restrict__ packed,
                        float* __restrict__ loss_slot) {
    __shared__ float tile[64][65];
    int bx = blockIdx.x;
    int t  = threadIdx.x;

    if (bx < 256) {                       // ---- zn-half role
        int p = t >> 1, h = t & 1;
        int n = bx * 128 + p;
        int b = n >> 10, hw = n & 1023;
        const float* base = z + (size_t)b * BSTRIDE + hw + (size_t)(h * 128) * HW;
        float r[8];
        #pragma unroll
        for (int j = 0; j < 8; ++j) {
            float v = base[(size_t)j * HW];
            r[j] = __fmul_rn(v, v);
        }
        #pragma unroll
        for (int i = 8; i < 128; i += 8) {
            #pragma unroll
            for (int j = 0; j < 8; ++j) {
                float v = base[(size_t)(i + j) * HW];
                r[j] = __fadd_rn(r[j], __fmul_rn(v, v));
            }
        }
        float half_s = __fadd_rn(
            __fadd_rn(__fadd_rn(r[0], r[1]), __fadd_rn(r[2], r[3])),
            __fadd_rn(__fadd_rn(r[4], r[5]), __fadd_rn(r[6], r[7])));
        ws_f[WS_ZN2 + 2 * n + h] = half_s;
        if (h == 0) packed[n] = 0xFFFFFFFFFFFFFFFFull;
        if (bx == 0 && t == 0) *loss_slot = 0.0f;
    } else if (bx < 260) {                // ---- en role
        int k = (bx - 256) * 256 + t;
        const float* row = cb + (size_t)k * DDIM;
        float half_s[2];
        #pragma unroll
        for (int h = 0; h < 2; ++h) {
            const float* p2 = row + h * 128;
            float r[8];
            #pragma unroll
            for (int j = 0; j < 8; ++j) r[j] = __fmul_rn(p2[j], p2[j]);
            #pragma unroll
            for (int i = 8; i < 128; i += 8) {
                #pragma unroll
                for (int j = 0; j < 8; ++j)
                    r[j] = __fadd_rn(r[j], __fmul_rn(p2[i + j], p2[i + j]));
            }
            half_s[h] = __fadd_rn(
                __fadd_rn(__fadd_rn(r[0], r[1]), __fadd_rn(r[2], r[3])),
                __fadd_rn(__fadd_rn(r[4], r[5]), __fadd_rn(r[6], r[7])));
        }
        ws_f[WS_EN + k] = __fadd_rn(half_s[0], half_s[1]);
    } else {                              // ---- transpose role
        int bt = bx - 260;
        int k0 = (bt & 15) * 64;
        int d0 = (bt >> 4) * 64;
        float* et = ws_f + WS_ET;
        #pragma unroll
        for (int p = 0; p < 4; ++p) {
            int r  = p * 16 + (t >> 4);
            int c4 = (t & 15) * 4;
            float4 v = *reinterpret_cast<const float4*>(
                cb + (size_t)(k0 + r) * DDIM + d0 + c4);
            tile[r][c4] = v.x; tile[r][c4+1] = v.y;
            tile[r][c4+2] = v.z; tile[r][c4+3] = v.w;
        }
        __syncthreads();
        #pragma unroll
        for (int s = 0; s < 16; ++s) {
            int dd = s * 4 + (t >> 6);
            int kk = t & 63;
            et[(size_t)(d0 + dd) * KCODE + k0 + kk] = tile[kk][dd];
        }
    }
}

// ---------------------------------------------------------------------------
// K2: distance-GEMM + argmin. Round-4 shape (256 thr, 64 pos x 256 codes,
// 8x8/thread) with B moved OFF the DS pipe: lane tx reads its 8 codes
// directly from ET (two coalesced global_load_dwordx4, L2-resident 1 MB
// table, software-pipelined one dk ahead). A stays LDS-staged (broadcast-
// shaped reads; proven). DS now carries only A: DS:VALU = 0.75 -> VALU-bound.
// Per-(n,k): sequential fmaf chain d=0..255 ascending, then
// fl(fl(zn+en)-fl(2*dot)) — BIT-IDENTICAL to verified rounds 3-7.
// Cross-block merge: atomicMin on (f32bits(d)<<32)|k (ties -> smaller k ==
// np.argmin first-index).
#define BM 64
#define BN 256
#define BK 16

__launch_bounds__(256, 4)
__global__ void vq_argmin(const float* __restrict__ z,
                          const float* __restrict__ ws_f,
                          unsigned long long* __restrict__ packed) {
    __shared__ float As[BK][64];     // [dk][pos]

    const float* ET  = ws_f + WS_ET;
    const float* zn2 = ws_f + WS_ZN2;
    const float* enW = ws_f + WS_EN;

    int t  = threadIdx.x;
    int tx = t & 31;                 // code group (8 codes each)
    int ty = t >> 5;                 // position group (8 positions each)
    int bc = blockIdx.x & 3;         // code-range quarter
    int bm = blockIdx.x >> 2;
    int kc = bc * BN;
    int n0 = bm * BM;
    int b  = n0 >> 10, hw0 = n0 & 1023;
    const float* zb = z + (size_t)b * BSTRIDE + hw0;
    const float* bp = ET + kc + 8 * tx;   // this lane's 8-code column base

    float acc[8][8];
    #pragma unroll
    for (int j = 0; j < 8; ++j)
        #pragma unroll
        for (int c = 0; c < 8; ++c) acc[j][c] = 0.0f;

    for (int d0 = 0; d0 < DDIM; d0 += BK) {
        __syncthreads();
        {   // stage A: 16x64 floats, 1 float4/thread
            int dk = t >> 4, p4 = (t & 15) << 2;
            float4 v = *reinterpret_cast<const float4*>(
                zb + (size_t)(d0 + dk) * HW + p4);
            As[dk][p4] = v.x; As[dk][p4+1] = v.y;
            As[dk][p4+2] = v.z; As[dk][p4+3] = v.w;
        }
        __syncthreads();

        // prefetch B row for dk=0
        float4 nb0 = *reinterpret_cast<const float4*>(bp + (size_t)d0 * KCODE);
        float4 nb1 = *reinterpret_cast<const float4*>(bp + (size_t)d0 * KCODE + 4);
        #pragma unroll
        for (int dk = 0; dk < BK; ++dk) {
            float4 b0 = nb0, b1 = nb1;
            if (dk < BK - 1) {   // prefetch next dk's B row
                nb0 = *reinterpret_cast<const float4*>(
                    bp + (size_t)(d0 + dk + 1) * KCODE);
                nb1 = *reinterpret_cast<const float4*>(
                    bp + (size_t)(d0 + dk + 1) * KCODE + 4);
            }
            float4 a0 = *reinterpret_cast<const float4*>(&As[dk][ty * 8]);
            float4 a1 = *reinterpret_cast<const float4*>(&As[dk][ty * 8 + 4]);
            float a[8]  = {a0.x, a0.y, a0.z, a0.w, a1.x, a1.y, a1.z, a1.w};
            float bb[8] = {b0.x, b0.y, b0.z, b0.w, b1.x, b1.y, b1.z, b1.w};
            #pragma unroll
            for (int j = 0; j < 8; ++j)
                #pragma unroll
                for (int c = 0; c < 8; ++c)
                    acc[j][c] = fmaf(a[j], bb[c], acc[j][c]);
        }
    }

    // epilogue: d = fl(fl(zn+en) - fl(2*dot)); strict < keeps first index
    float znr[8];
    #pragma unroll
    for (int j = 0; j < 8; ++j) {
        int n = n0 + ty * 8 + j;
        znr[j] = __fadd_rn(zn2[2 * n], zn2[2 * n + 1]);
    }
    float4 e0 = *reinterpret_cast<const float4*>(enW + kc + 8 * tx);
    float4 e1 = *reinterpret_cast<const float4*>(enW + kc + 8 * tx + 4);
    float en8[8] = {e0.x, e0.y, e0.z, e0.w, e1.x, e1.y, e1.z, e1.w};

    float m1[8];
    int   i1[8];
    #pragma unroll
    for (int j = 0; j < 8; ++j) { m1[j] = 1e30f; i1[j] = 0; }
    #pragma unroll
    for (int c = 0; c < 8; ++c) {
        int k = kc + 8 * tx + c;
        float ek = en8[c];
        #pragma unroll
        for (int j = 0; j < 8; ++j) {
            float t1 = __fadd_rn(znr[j], ek);
            float d  = __fsub_rn(t1, __fmul_rn(2.0f, acc[j][c]));
            if (d < m1[j]) { m1[j] = d; i1[j] = k; }
        }
    }

    // cross-lane argmin over the 32 tx lanes (smaller index wins ties)
    #pragma unroll
    for (int j = 0; j < 8; ++j) {
        float a1v = m1[j];
        int   ii  = i1[j];
        #pragma unroll
        for (int off = 1; off < 32; off <<= 1) {
            float o1 = __shfl_xor(a1v, off, 32);
            int   oi = __shfl_xor(ii, off, 32);
            if (o1 < a1v || (o1 == a1v && oi < ii)) { a1v = o1; ii = oi; }
        }
        if (tx == 0) {
            unsigned long long key =
                ((unsigned long long)__float_as_uint(a1v) << 32) |
                (unsigned long long)(unsigned)ii;
            atomicMin(&packed[n0 + ty * 8 + j], key);
        }
    }
}

// ---------------------------------------------------------------------------
// K3: index extract + gather zq + transpose to (B,D,H,W) + loss.
// grid 512 blocks x 256 threads: block = 64 positions x 4 d-chunks of 64.
__global__ void vq_gather(const float* __restrict__ z,
                          const float* __restrict__ cb,
                          const unsigned long long* __restrict__ packed,
                          float* __restrict__ out,
                          float* __restrict__ loss) {
    int t  = threadIdx.x;
    int p  = t & 63, dc = t >> 6;
    int n  = blockIdx.x * 64 + p;
    int b  = n >> 10, hw = n & 1023;
    int k  = (int)(unsigned)(packed[n] & 0xFFFFFFFFull);
    size_t off = (size_t)b * BSTRIDE + hw + (size_t)(dc * 64) * HW;
    const float* e  = cb + (size_t)k * DDIM + dc * 64;
    const float* zp = z + off;
    float* op = out + off;
    float s = 0.0f;
    #pragma unroll 4
    for (int d4 = 0; d4 < 16; ++d4) {
        float4 ev = *reinterpret_cast<const float4*>(e + 4 * d4);
        float evs[4] = {ev.x, ev.y, ev.z, ev.w};
        #pragma unroll
        for (int q = 0; q < 4; ++q) {
            int d = 4 * d4 + q;
            float zv = zp[(size_t)d * HW];
            op[(size_t)d * HW] = evs[q];
            float df = evs[q] - zv;
            s = fmaf(df, df, s);
        }
    }
    if (dc == 0) out[OUT0_SIZE + n] = (float)k;

    #pragma unroll
    for (int o = 32; o > 0; o >>= 1) s += __shfl_down(s, o);
    __shared__ float red[4];
    int lane = t & 63, w = t >> 6;
    if (lane == 0) red[w] = s;
    __syncthreads();
    if (t == 0) {
        float tot = (red[0] + red[1] + red[2] + red[3]) * (2.0f / 8388608.0f);
        atomicAdd(loss, tot);
    }
}

// ---------------------------------------------------------------------------
extern "C" void kernel_launch(void* const* d_in, const int* in_sizes, int n_in,
                              void* d_out, int out_size, void* d_ws, size_t ws_size,
                              hipStream_t stream) {
    const float* z  = (const float*)d_in[0];
    const float* cb = (const float*)d_in[1];
    float* out  = (float*)d_out;
    float* ws_f = (float*)d_ws;
    unsigned long long* packed =
        (unsigned long long*)(ws_f + WS_PACKED);
    float* loss = out + OUT0_SIZE + OUT1_SIZE;

    vq_prep<<<324, 256, 0, stream>>>(z, cb, ws_f, packed, loss);
    vq_argmin<<<(NPOS / BM) * (KCODE / BN), 256, 0, stream>>>(z, ws_f, packed);
    vq_gather<<<NPOS / 64, 256, 0, stream>>>(z, cb, packed, out, loss);
}

// Round 9
// 312.787 us; speedup vs baseline: 1.2834x; 1.2834x over previous
//
#include <hip/hip_runtime.h>

// Problem constants
#define NPOS 32768          // B*H*W = 32*32*32
#define DDIM 256
#define KCODE 1024
#define HW 1024             // H*W
#define BSTRIDE (256*1024)  // D*H*W per batch element
#define OUT0_SIZE 8388608   // B*D*H*W
#define OUT1_SIZE 32768

// ws layout (4-byte units):
//  [0 .. 262143]        ET    : transposed codebook [d][k]        (float)
//  [262144 .. 327679]   zn2   : per-position pairwise HALVES      (float, 2*32768)
//  [327680 .. 328703]   en    : ||e_k||^2 numpy-pairwise f32      (float, 1024)
//  [328704 .. 394239]   packed: (f32bits(d)<<32)|k per pos        (u64, 32768)
#define WS_ET     0
#define WS_ZN2    262144
#define WS_EN     327680
#define WS_PACKED 328704   // *4 bytes is 8-aligned

// ---------------------------------------------------------------------------
// K1: fused prep. grid 324 blocks x 256 threads:
//   [0,256)   : zn halves (numpy pairwise 128-blocks) + packed init (+loss 0)
//   [256,260) : en[k] numpy-pairwise
//   [260,324) : 64x64 LDS-tiled transpose cb -> ET
// numpy pairwise for n=256 = fl(half0+half1); halves computed in separate
// threads (bitwise-identical chains), merged with __fadd_rn in vq_argmin.
__global__ void vq_prep(const float* __restrict__ z,
                        const float* __restrict__ cb,
                        float* __restrict__ ws_f,
                        unsigned long long* __restrict__ packed,
                        float* __restrict__ loss_slot) {
    __shared__ float tile[64][65];
    int bx = blockIdx.x;
    int t  = threadIdx.x;

    if (bx < 256) {                       // ---- zn-half role
        int p = t >> 1, h = t & 1;
        int n = bx * 128 + p;
        int b = n >> 10, hw = n & 1023;
        const float* base = z + (size_t)b * BSTRIDE + hw + (size_t)(h * 128) * HW;
        float r[8];
        #pragma unroll
        for (int j = 0; j < 8; ++j) {
            float v = base[(size_t)j * HW];
            r[j] = __fmul_rn(v, v);
        }
        #pragma unroll
        for (int i = 8; i < 128; i += 8) {
            #pragma unroll
            for (int j = 0; j < 8; ++j) {
                float v = base[(size_t)(i + j) * HW];
                r[j] = __fadd_rn(r[j], __fmul_rn(v, v));
            }
        }
        float half_s = __fadd_rn(
            __fadd_rn(__fadd_rn(r[0], r[1]), __fadd_rn(r[2], r[3])),
            __fadd_rn(__fadd_rn(r[4], r[5]), __fadd_rn(r[6], r[7])));
        ws_f[WS_ZN2 + 2 * n + h] = half_s;
        if (h == 0) packed[n] = 0xFFFFFFFFFFFFFFFFull;
        if (bx == 0 && t == 0) *loss_slot = 0.0f;
    } else if (bx < 260) {                // ---- en role
        int k = (bx - 256) * 256 + t;
        const float* row = cb + (size_t)k * DDIM;
        float half_s[2];
        #pragma unroll
        for (int h = 0; h < 2; ++h) {
            const float* p2 = row + h * 128;
            float r[8];
            #pragma unroll
            for (int j = 0; j < 8; ++j) r[j] = __fmul_rn(p2[j], p2[j]);
            #pragma unroll
            for (int i = 8; i < 128; i += 8) {
                #pragma unroll
                for (int j = 0; j < 8; ++j)
                    r[j] = __fadd_rn(r[j], __fmul_rn(p2[i + j], p2[i + j]));
            }
            half_s[h] = __fadd_rn(
                __fadd_rn(__fadd_rn(r[0], r[1]), __fadd_rn(r[2], r[3])),
                __fadd_rn(__fadd_rn(r[4], r[5]), __fadd_rn(r[6], r[7])));
        }
        ws_f[WS_EN + k] = __fadd_rn(half_s[0], half_s[1]);
    } else {                              // ---- transpose role
        int bt = bx - 260;
        int k0 = (bt & 15) * 64;
        int d0 = (bt >> 4) * 64;
        float* et = ws_f + WS_ET;
        #pragma unroll
        for (int p = 0; p < 4; ++p) {
            int r  = p * 16 + (t >> 4);
            int c4 = (t & 15) * 4;
            float4 v = *reinterpret_cast<const float4*>(
                cb + (size_t)(k0 + r) * DDIM + d0 + c4);
            tile[r][c4] = v.x; tile[r][c4+1] = v.y;
            tile[r][c4+2] = v.z; tile[r][c4+3] = v.w;
        }
        __syncthreads();
        #pragma unroll
        for (int s = 0; s < 16; ++s) {
            int dd = s * 4 + (t >> 6);
            int kk = t & 63;
            et[(size_t)(d0 + dd) * KCODE + k0 + kk] = tile[kk][dd];
        }
    }
}

// ---------------------------------------------------------------------------
// K2: distance-GEMM + argmin. All-LDS (the only transport that hasn't lost),
// register blocking enlarged P=16 pos x C=8 codes per thread to cut DS
// reads/FMA from 0.25 to 0.1875 (R4 was DS-pipe-bound at ratio 1.5; this is
// ~1.2). Block: 256 thr = (ty 8 x tx 32); tile BM=128 pos x BN=256 codes
// (kc quarter), BK=16. Bs uses the proven 9/8 skew (lane tx reads at 9*tx
// floats -> conflict-free); As reads are ty-only addresses -> broadcast.
// Per-(n,k): sequential fmaf chain d=0..255 ascending, then
// fl(fl(zn+en)-fl(2*dot)) — BIT-IDENTICAL to verified rounds 3-8.
// Cross-block merge: atomicMin on (f32bits(d)<<32)|k (ties -> smaller k ==
// np.argmin first-index).
#define BM 128
#define BN 256
#define BK 16
#define BSKEW(k) ((k) + ((k) >> 3))   // max 255+31=286 -> row len 288

__launch_bounds__(256, 2)
__global__ void vq_argmin(const float* __restrict__ z,
                          const float* __restrict__ ws_f,
                          unsigned long long* __restrict__ packed) {
    __shared__ float As[BK][128];    // [dk][pos]
    __shared__ float Bs[BK][288];    // [dk][skewed code]

    const float* ET  = ws_f + WS_ET;
    const float* zn2 = ws_f + WS_ZN2;
    const float* enW = ws_f + WS_EN;

    int t  = threadIdx.x;
    int tx = t & 31;                 // code group (8 codes each)
    int ty = t >> 5;                 // position group (16 positions each)
    int bc = blockIdx.x & 3;         // code-range quarter
    int bm = blockIdx.x >> 2;
    int kc = bc * BN;
    int n0 = bm * BM;                // 128 | 1024 -> single batch row
    int b  = n0 >> 10, hw0 = n0 & 1023;
    const float* zb = z + (size_t)b * BSTRIDE + hw0;

    float acc[16][8];
    #pragma unroll
    for (int j = 0; j < 16; ++j)
        #pragma unroll
        for (int c = 0; c < 8; ++c) acc[j][c] = 0.0f;

    for (int d0 = 0; d0 < DDIM; d0 += BK) {
        __syncthreads();
        #pragma unroll
        for (int i = 0; i < 2; ++i) {   // stage A: 16x128 floats, 2 f4/thread
            int q = t + i * 256;
            int dk = q >> 5, p4 = (q & 31) << 2;
            float4 v = *reinterpret_cast<const float4*>(
                zb + (size_t)(d0 + dk) * HW + p4);
            As[dk][p4] = v.x; As[dk][p4+1] = v.y;
            As[dk][p4+2] = v.z; As[dk][p4+3] = v.w;
        }
        #pragma unroll
        for (int i = 0; i < 4; ++i) {   // stage B: 16x256 floats, skewed
            int q = t + i * 256;
            int dk = q >> 6, m = q & 63;          // codes 4m..4m+3
            float4 v = *reinterpret_cast<const float4*>(
                ET + (size_t)(d0 + dk) * KCODE + kc + 4 * m);
            int ph = BSKEW(4 * m);
            *reinterpret_cast<float4*>(&Bs[dk][ph]) = v;
        }
        __syncthreads();

        #pragma unroll
        for (int dk = 0; dk < BK; ++dk) {
            float4 a0 = *reinterpret_cast<const float4*>(&As[dk][ty * 16]);
            float4 a1 = *reinterpret_cast<const float4*>(&As[dk][ty * 16 + 4]);
            float4 a2 = *reinterpret_cast<const float4*>(&As[dk][ty * 16 + 8]);
            float4 a3 = *reinterpret_cast<const float4*>(&As[dk][ty * 16 + 12]);
            float4 b0 = *reinterpret_cast<const float4*>(&Bs[dk][9 * tx]);
            float4 b1 = *reinterpret_cast<const float4*>(&Bs[dk][9 * tx + 4]);
            float a[16] = {a0.x, a0.y, a0.z, a0.w, a1.x, a1.y, a1.z, a1.w,
                           a2.x, a2.y, a2.z, a2.w, a3.x, a3.y, a3.z, a3.w};
            float bb[8] = {b0.x, b0.y, b0.z, b0.w, b1.x, b1.y, b1.z, b1.w};
            #pragma unroll
            for (int j = 0; j < 16; ++j)
                #pragma unroll
                for (int c = 0; c < 8; ++c)
                    acc[j][c] = fmaf(a[j], bb[c], acc[j][c]);
        }
    }

    // epilogue: d = fl(fl(zn+en) - fl(2*dot)); strict < keeps first index
    float znr[16];
    #pragma unroll
    for (int j = 0; j < 16; ++j) {
        int n = n0 + ty * 16 + j;
        znr[j] = __fadd_rn(zn2[2 * n], zn2[2 * n + 1]);
    }
    float4 e0 = *reinterpret_cast<const float4*>(enW + kc + 8 * tx);
    float4 e1 = *reinterpret_cast<const float4*>(enW + kc + 8 * tx + 4);
    float en8[8] = {e0.x, e0.y, e0.z, e0.w, e1.x, e1.y, e1.z, e1.w};

    float m1[16];
    int   i1[16];
    #pragma unroll
    for (int j = 0; j < 16; ++j) { m1[j] = 1e30f; i1[j] = 0; }
    #pragma unroll
    for (int c = 0; c < 8; ++c) {
        int k = kc + 8 * tx + c;
        float ek = en8[c];
        #pragma unroll
        for (int j = 0; j < 16; ++j) {
            float t1 = __fadd_rn(znr[j], ek);
            float d  = __fsub_rn(t1, __fmul_rn(2.0f, acc[j][c]));
            if (d < m1[j]) { m1[j] = d; i1[j] = k; }
        }
    }

    // cross-lane argmin over the 32 tx lanes (smaller index wins ties)
    #pragma unroll
    for (int j = 0; j < 16; ++j) {
        float a1v = m1[j];
        int   ii  = i1[j];
        #pragma unroll
        for (int off = 1; off < 32; off <<= 1) {
            float o1 = __shfl_xor(a1v, off, 32);
            int   oi = __shfl_xor(ii, off, 32);
            if (o1 < a1v || (o1 == a1v && oi < ii)) { a1v = o1; ii = oi; }
        }
        if (tx == 0) {
            unsigned long long key =
                ((unsigned long long)__float_as_uint(a1v) << 32) |
                (unsigned long long)(unsigned)ii;
            atomicMin(&packed[n0 + ty * 16 + j], key);
        }
    }
}

// ---------------------------------------------------------------------------
// K3: index extract + gather zq + transpose to (B,D,H,W) + loss.
// grid 512 blocks x 256 threads: block = 64 positions x 4 d-chunks of 64.
__global__ void vq_gather(const float* __restrict__ z,
                          const float* __restrict__ cb,
                          const unsigned long long* __restrict__ packed,
                          float* __restrict__ out,
                          float* __restrict__ loss) {
    int t  = threadIdx.x;
    int p  = t & 63, dc = t >> 6;
    int n  = blockIdx.x * 64 + p;
    int b  = n >> 10, hw = n & 1023;
    int k  = (int)(unsigned)(packed[n] & 0xFFFFFFFFull);
    size_t off = (size_t)b * BSTRIDE + hw + (size_t)(dc * 64) * HW;
    const float* e  = cb + (size_t)k * DDIM + dc * 64;
    const float* zp = z + off;
    float* op = out + off;
    float s = 0.0f;
    #pragma unroll 4
    for (int d4 = 0; d4 < 16; ++d4) {
        float4 ev = *reinterpret_cast<const float4*>(e + 4 * d4);
        float evs[4] = {ev.x, ev.y, ev.z, ev.w};
        #pragma unroll
        for (int q = 0; q < 4; ++q) {
            int d = 4 * d4 + q;
            float zv = zp[(size_t)d * HW];
            op[(size_t)d * HW] = evs[q];
            float df = evs[q] - zv;
            s = fmaf(df, df, s);
        }
    }
    if (dc == 0) out[OUT0_SIZE + n] = (float)k;

    #pragma unroll
    for (int o = 32; o > 0; o >>= 1) s += __shfl_down(s, o);
    __shared__ float red[4];
    int lane = t & 63, w = t >> 6;
    if (lane == 0) red[w] = s;
    __syncthreads();
    if (t == 0) {
        float tot = (red[0] + red[1] + red[2] + red[3]) * (2.0f / 8388608.0f);
        atomicAdd(loss, tot);
    }
}

// ---------------------------------------------------------------------------
extern "C" void kernel_launch(void* const* d_in, const int* in_sizes, int n_in,
                              void* d_out, int out_size, void* d_ws, size_t ws_size,
                              hipStream_t stream) {
    const float* z  = (const float*)d_in[0];
    const float* cb = (const float*)d_in[1];
    float* out  = (float*)d_out;
    float* ws_f = (float*)d_ws;
    unsigned long long* packed =
        (unsigned long long*)(ws_f + WS_PACKED);
    float* loss = out + OUT0_SIZE + OUT1_SIZE;

    vq_prep<<<324, 256, 0, stream>>>(z, cb, ws_f, packed, loss);
    vq_argmin<<<(NPOS / BM) * (KCODE / BN), 256, 0, stream>>>(z, ws_f, packed);
    vq_gather<<<NPOS / 64, 256, 0, stream>>>(z, cb, packed, out, loss);
}